// Round 10
// baseline (1574.873 us; speedup 1.0000x reference)
//
#include <hip/hip_runtime.h>
#include <math.h>

#define TOK   16384
#define HID   2048
#define INTER 8192
#define NPART 8

typedef __attribute__((ext_vector_type(8))) short short8;
typedef __attribute__((ext_vector_type(4))) float f32x4;

__device__ inline ushort f2bf(float f){
  union{float f; unsigned u;} v; v.f=f;
  unsigned r = v.u + 0x7FFFu + ((v.u>>16)&1u);
  return (ushort)(r>>16);
}

// ---------------- fp32 -> bf16 convert (row-major copy) ----------------
__global__ __launch_bounds__(256) void cvt_f32_bf16(const float* __restrict__ in,
                                                    ushort* __restrict__ out, int n4)
{
  int idx = blockIdx.x*blockDim.x + threadIdx.x;
  int stride = gridDim.x*blockDim.x;
  for (int i = idx; i < n4; i += stride) {
    float4 v = ((const float4*)in)[i];
    ushort4 o;
    o.x = f2bf(v.x); o.y = f2bf(v.y); o.z = f2bf(v.z); o.w = f2bf(v.w);
    ((ushort4*)out)[i] = o;
  }
}

// ---------------- transpose + convert: in[R][C] f32 -> out[C][R] bf16 ----------------
__global__ __launch_bounds__(256) void trans_cvt(const float* __restrict__ in,
                                                 ushort* __restrict__ out, int R, int C)
{
  __shared__ float t[32][33];
  int tx = threadIdx.x & 31, ty = threadIdx.x >> 5;
  int c0 = blockIdx.x*32, r0 = blockIdx.y*32;
  #pragma unroll
  for (int i = 0; i < 4; i++)
    t[ty + i*8][tx] = in[(size_t)(r0 + ty + i*8)*C + c0 + tx];
  __syncthreads();
  #pragma unroll
  for (int i = 0; i < 4; i++)
    out[(size_t)(c0 + ty + i*8)*R + r0 + tx] = f2bf(t[tx][ty + i*8]);
}

// ---------------- pack W[K][16] f32 -> B-fragment layout bf16 (LoRA) ----------------
__global__ __launch_bounds__(256) void pack_w(const float* __restrict__ W,
                                              ushort* __restrict__ out, int K)
{
  int tid = blockIdx.x*256 + threadIdx.x;
  int n = (K >> 5) * 64;
  if (tid >= n) return;
  int step = tid >> 6, l = tid & 63;
  int col = l & 15, kb = step*32 + ((l >> 4) << 3);
  ushort4 o0, o1;
  o0.x = f2bf(W[(size_t)(kb+0)*16 + col]);
  o0.y = f2bf(W[(size_t)(kb+1)*16 + col]);
  o0.z = f2bf(W[(size_t)(kb+2)*16 + col]);
  o0.w = f2bf(W[(size_t)(kb+3)*16 + col]);
  o1.x = f2bf(W[(size_t)(kb+4)*16 + col]);
  o1.y = f2bf(W[(size_t)(kb+5)*16 + col]);
  o1.z = f2bf(W[(size_t)(kb+6)*16 + col]);
  o1.w = f2bf(W[(size_t)(kb+7)*16 + col]);
  ((ushort4*)(out + (size_t)tid*8))[0] = o0;
  ((ushort4*)(out + (size_t)tid*8))[1] = o1;
}

// ---------------- rank-16 contract via MFMA, split-K partials ----------------
__global__ __launch_bounds__(256) void lora_in_mfma(const ushort* __restrict__ x,
                                                    const ushort* __restrict__ Wpk,
                                                    float* __restrict__ tpart,
                                                    int M, int K)
{
  const int l  = threadIdx.x & 63;
  const int wv = threadIdx.x >> 6;
  const int jid = blockIdx.x*4 + wv;
  const int nt = M >> 4;
  const int part = jid >> 10;
  const int tile = jid & (nt - 1);
  const int Kc = K / NPART;
  const int k0 = part * Kc;
  const int fr = l & 15, fq = l >> 4;

  const ushort* xp = x + (size_t)(tile*16 + fr)*K + k0 + fq*8;
  const ushort* wp = Wpk + (size_t)(k0 >> 5)*512 + l*8;

  f32x4 acc = (f32x4){0.f,0.f,0.f,0.f};
  const int ns = Kc >> 5;
  for (int s = 0; s < ns; ++s) {
    short8 av = *(const short8*)(xp + s*32);
    short8 bv = *(const short8*)(wp + s*512);
    acc = __builtin_amdgcn_mfma_f32_16x16x32_bf16(av, bv, acc, 0, 0, 0);
  }
  float* o = tpart + ((size_t)part*M + tile*16)*16;
  #pragma unroll
  for (int r = 0; r < 4; ++r) o[(fq*4 + r)*16 + fr] = acc[r];
}

// ---------------- rank-16 expand: out[N][W] = (sum_p tpart[p]) @ Bm[16][W] ----------------
__global__ __launch_bounds__(256) void lora_out(const float* __restrict__ tpart,
                                                const float* __restrict__ Bm,
                                                float* __restrict__ out, int W, int M)
{
  __shared__ float ts[8][16];
  int tid = threadIdx.x;
  int n0 = blockIdx.y*8, i0 = blockIdx.x*1024;
  if (tid < 128) {
    float s = 0.f;
    #pragma unroll
    for (int p = 0; p < NPART; ++p)
      s += tpart[((size_t)p*M + n0 + (tid>>4))*16 + (tid&15)];
    ts[tid>>4][tid&15] = s;
  }
  __syncthreads();
  const float4* B4 = (const float4*)Bm;
  float4 breg[16];
  #pragma unroll
  for (int r = 0; r < 16; r++) breg[r] = B4[(size_t)r*(W>>2) + (i0>>2) + tid];
  #pragma unroll
  for (int n = 0; n < 8; n++) {
    float4 o; o.x = o.y = o.z = o.w = 0.f;
    #pragma unroll
    for (int r = 0; r < 16; r++) {
      float s = ts[n][r];
      o.x += s*breg[r].x; o.y += s*breg[r].y; o.z += s*breg[r].z; o.w += s*breg[r].w;
    }
    ((float4*)(out + (size_t)(n0+n)*W + i0))[tid] = o;
  }
}

// =====================================================================
// m201-template 256x256 bf16 MFMA GEMM, BK=64, 8 waves (2Mx4N).
// 2-deep LDS double-buffer (128 KB), 4 phases/K-tile (16 MFMA each,
// quadrant decomposition with operand reuse: 12/4/8/0 ds_reads/phase),
// 1 half-tile staged per phase, ONE counted vmcnt(4) per K-tile,
// XOR bank swizzle, setprio, swapped-operand vectorized stores.
// C = A[M][K] @ BT[N][K]^T + bias.  EPI=0: gelu->bf16; EPI=1: f32.
// =====================================================================
template<int EPI>
__global__ __launch_bounds__(512, 2)
void gemm_bt(const ushort* __restrict__ A,
             const ushort* __restrict__ BT,
             const float* __restrict__ bias,
             ushort* __restrict__ outb,
             float* __restrict__ outf,
             int M, int N, int K, int grid_n)
{
  // buffer: A[256][64] (32 KB) + B[256][64] (32 KB); x2 dbuf = 128 KB
  __shared__ __align__(16) ushort lds[2][32768];

  const int tid = threadIdx.x;
  const int l   = tid & 63;
  const int w   = tid >> 6;
  const int wr  = w >> 2;            // 0..1 (M half: 128 rows)
  const int wc  = w & 3;             // 0..3 (N quarter: 64 cols)

  const int nwg = gridDim.x;
  const int cpx = nwg >> 3;
  const int bid = blockIdx.x;
  const int wg  = (bid & 7) * cpx + (bid >> 3);
  const int bx  = wg % grid_n;
  const int by  = wg / grid_n;

  // staging: 512 threads x 16B = 64 rows x 128B per round; 2 rounds per half-tile
  // global source pre-swizzled (inverse of read-side XOR within each 32-elem k-step)
  const int srow8 = tid >> 3;                                // 0..63
  const int scol8 = (((tid & 7) ^ ((tid >> 4) & 3)) << 3);   // element offset
  const ushort* agp = A  + (size_t)(by*256 + srow8)*K + scol8;
  const ushort* bgp = BT + (size_t)(bx*256 + srow8)*K + scol8;

  // fragment read offsets (swizzled); row stride 64 elem (128 B)
  const int fr  = l & 15, fq = l >> 4;
  const int swz = fq ^ ((fr >> 1) & 3);
  const int aoff = (wr*128 + fr)*64 + swz*8;            // + m*1024 + k*32
  const int boff = 16384 + (wc*64 + fr)*64 + swz*8;     // + n*1024 + k*32

  f32x4 acc[8][4];
  #pragma unroll
  for (int m = 0; m < 8; m++)
    #pragma unroll
    for (int n = 0; n < 4; n++) acc[m][n] = (f32x4){0.f,0.f,0.f,0.f};

  auto stA = [&](int u, int h) {     // A-half h (rows h*128..+127) of tile u
    ushort* d = &lds[u & 1][h*8192 + tid*8];
    const ushort* s = agp + (size_t)(h*128)*K + (size_t)u*64;
    __builtin_amdgcn_global_load_lds((const __attribute__((address_space(1))) void*)s,
                                     (__attribute__((address_space(3))) void*)d, 16, 0, 0);
    __builtin_amdgcn_global_load_lds((const __attribute__((address_space(1))) void*)(s + (size_t)64*K),
                                     (__attribute__((address_space(3))) void*)(d + 4096), 16, 0, 0);
  };
  auto stB = [&](int u, int h) {
    ushort* d = &lds[u & 1][16384 + h*8192 + tid*8];
    const ushort* s = bgp + (size_t)(h*128)*K + (size_t)u*64;
    __builtin_amdgcn_global_load_lds((const __attribute__((address_space(1))) void*)s,
                                     (__attribute__((address_space(3))) void*)d, 16, 0, 0);
    __builtin_amdgcn_global_load_lds((const __attribute__((address_space(1))) void*)(s + (size_t)64*K),
                                     (__attribute__((address_space(3))) void*)(d + 4096), 16, 0, 0);
  };

  const int nk = K >> 6;   // K-tiles of 64; >= 32 here

  // prologue: stage A(0), B(0), B(1); certify A(0)+B(0) (counted vmcnt)
  stA(0,0); stA(0,1); stB(0,0); stB(0,1); stB(1,0); stB(1,1);
  asm volatile("s_waitcnt vmcnt(4)" ::: "memory");
  __builtin_amdgcn_s_barrier();
  asm volatile("" ::: "memory");

  short8 a[8], b[8];

#define MFMA16(MBASE, NBASE) do {                                         \
    __builtin_amdgcn_s_setprio(1);                                        \
    _Pragma("unroll")                                                     \
    for (int m_ = 0; m_ < 4; ++m_)                                        \
      _Pragma("unroll")                                                   \
      for (int k_ = 0; k_ < 2; ++k_)                                      \
        _Pragma("unroll")                                                 \
        for (int n_ = 0; n_ < 2; ++n_)                                    \
          acc[MBASE + m_][NBASE + n_] = __builtin_amdgcn_mfma_f32_16x16x32_bf16( \
              b[(NBASE + n_)*2 + k_], a[m_*2 + k_], acc[MBASE + m_][NBASE + n_], 0,0,0); \
    __builtin_amdgcn_s_setprio(0);                                        \
  } while (0)

  for (int kt = 0; kt < nk; ++kt) {
    const ushort* Lb = &lds[kt & 1][0];

    // ---- phase 1: read A(m0-3,k0-1) + B(n0-1,k0-1); stage A(kt+1,h0); Q1 ----
    #pragma unroll
    for (int m = 0; m < 4; ++m)
      #pragma unroll
      for (int k = 0; k < 2; ++k)
        a[m*2+k] = *(const short8*)(Lb + aoff + m*1024 + k*32);
    #pragma unroll
    for (int n = 0; n < 2; ++n)
      #pragma unroll
      for (int k = 0; k < 2; ++k)
        b[n*2+k] = *(const short8*)(Lb + boff + n*1024 + k*32);
    if (kt + 1 < nk) stA(kt+1, 0);
    __builtin_amdgcn_s_barrier();
    asm volatile("s_waitcnt lgkmcnt(0)" ::: "memory");
    __builtin_amdgcn_sched_barrier(0);
    MFMA16(0, 0);
    __builtin_amdgcn_s_barrier();
    asm volatile("" ::: "memory");

    // ---- phase 2: read B(n2-3,k0-1); stage A(kt+1,h1); Q2 ----
    #pragma unroll
    for (int n = 2; n < 4; ++n)
      #pragma unroll
      for (int k = 0; k < 2; ++k)
        b[n*2+k] = *(const short8*)(Lb + boff + n*1024 + k*32);
    if (kt + 1 < nk) stA(kt+1, 1);
    __builtin_amdgcn_s_barrier();
    asm volatile("s_waitcnt lgkmcnt(0)" ::: "memory");
    __builtin_amdgcn_sched_barrier(0);
    MFMA16(0, 2);
    __builtin_amdgcn_s_barrier();
    asm volatile("" ::: "memory");

    // ---- phase 3: read A(m4-7,k0-1); stage B(kt+2,h0); Q3 ----
    #pragma unroll
    for (int m = 0; m < 4; ++m)
      #pragma unroll
      for (int k = 0; k < 2; ++k)
        a[m*2+k] = *(const short8*)(Lb + aoff + (m+4)*1024 + k*32);
    if (kt + 2 < nk) stB(kt+2, 0);
    __builtin_amdgcn_s_barrier();
    asm volatile("s_waitcnt lgkmcnt(0)" ::: "memory");
    __builtin_amdgcn_sched_barrier(0);
    MFMA16(4, 0);
    __builtin_amdgcn_s_barrier();
    asm volatile("" ::: "memory");

    // ---- phase 4: no reads; stage B(kt+2,h1); Q4; boundary ----
    if (kt + 2 < nk) stB(kt+2, 1);
    __builtin_amdgcn_s_barrier();
    asm volatile("" ::: "memory");
    MFMA16(4, 2);
    if (kt + 1 < nk) {
      if (kt + 2 < nk) asm volatile("s_waitcnt vmcnt(4)" ::: "memory");
      else             asm volatile("s_waitcnt vmcnt(0)" ::: "memory");
      __builtin_amdgcn_s_barrier();
      asm volatile("" ::: "memory");
    }
  }

#undef MFMA16

  // ---- epilogue: lane&15 = M-row, (lane>>4)*4+r = N-col -> vector stores ----
  #pragma unroll
  for (int m = 0; m < 8; ++m) {
    const int rowg = by*256 + wr*128 + m*16 + fr;
    #pragma unroll
    for (int n = 0; n < 4; ++n) {
      const int colg = bx*256 + wc*64 + n*16 + fq*4;
      const float4 bv = *(const float4*)&bias[colg];
      float v0 = acc[m][n][0] + bv.x;
      float v1 = acc[m][n][1] + bv.y;
      float v2 = acc[m][n][2] + bv.z;
      float v3 = acc[m][n][3] + bv.w;
      if (EPI == 0) {
        #define GELU(v) do { \
          float u_ = 0.7978845608028654f*((v) + 0.044715f*(v)*(v)*(v)); \
          float e_ = __builtin_amdgcn_exp2f(-2.8853900817779268f*u_);   \
          (v) = (v) * __builtin_amdgcn_rcpf(1.0f + e_); } while(0)
        GELU(v0); GELU(v1); GELU(v2); GELU(v3);
        #undef GELU
        ushort4 o; o.x = f2bf(v0); o.y = f2bf(v1); o.z = f2bf(v2); o.w = f2bf(v3);
        *(ushort4*)&outb[(size_t)rowg*N + colg] = o;
      } else {
        float4 o; o.x = v0; o.y = v1; o.z = v2; o.w = v3;
        *(float4*)&outf[(size_t)rowg*N + colg] = o;
      }
    }
  }
}

extern "C" void kernel_launch(void* const* d_in, const int* in_sizes, int n_in,
                              void* d_out, int out_size, void* d_ws, size_t ws_size,
                              hipStream_t stream)
{
  const float* hid  = (const float*)d_in[0];
  const float* Wfc  = (const float*)d_in[1];
  const float* bfc  = (const float*)d_in[2];
  const float* Wpj  = (const float*)d_in[3];
  const float* bpj  = (const float*)d_in[4];
  const float* Amat = (const float*)d_in[5];
  const float* Bmat = (const float*)d_in[6];
  const float* Cmat = (const float*)d_in[7];
  const float* Dmat = (const float*)d_in[8];

  float* out = (float*)d_out;                  // [TOK][HID]
  float* ab  = out + (size_t)TOK*HID;          // [TOK][INTER]
  float* cd  = ab  + (size_t)TOK*INTER;        // [TOK][HID]

  char* ws = (char*)d_ws;
  ushort* hidb = (ushort*)ws;  ws += (size_t)TOK*HID*2;
  ushort* wfct = (ushort*)ws;  ws += (size_t)INTER*HID*2;
  ushort* wpjt = (ushort*)ws;  ws += (size_t)HID*INTER*2;
  ushort* hbf  = (ushort*)ws;  ws += (size_t)TOK*INTER*2;
  ushort* apk  = (ushort*)ws;  ws += (size_t)HID*16*2;
  ushort* cpk  = (ushort*)ws;  ws += (size_t)INTER*16*2;
  float*  tpab = (float*)ws;   ws += (size_t)NPART*TOK*16*4;
  float*  tpcd = (float*)ws;   ws += (size_t)NPART*TOK*16*4;

  // independent pre-passes
  cvt_f32_bf16<<<4096, 256, 0, stream>>>(hid, hidb, TOK*HID/4);
  trans_cvt<<<dim3(INTER/32, HID/32), 256, 0, stream>>>(Wfc, wfct, HID, INTER);
  trans_cvt<<<dim3(HID/32, INTER/32), 256, 0, stream>>>(Wpj, wpjt, INTER, HID);
  pack_w<<<((HID/32)*64 + 255)/256, 256, 0, stream>>>(Amat, apk, HID);
  pack_w<<<((INTER/32)*64 + 255)/256, 256, 0, stream>>>(Cmat, cpk, INTER);

  // t_ab partials = hidden @ A
  lora_in_mfma<<<(TOK/16)*NPART/4, 256, 0, stream>>>(hidb, apk, tpab, TOK, HID);

  // h = gelu(hidden @ W_fc + b_fc), stored bf16
  gemm_bt<0><<<(TOK/256)*(INTER/256), 512, 0, stream>>>(
      hidb, wfct, bfc, hbf, nullptr, TOK, INTER, HID, INTER/256);

  // ab_out = (hidden @ A) @ B
  lora_out<<<dim3(INTER/1024, TOK/8), 256, 0, stream>>>(tpab, Bmat, ab, INTER, TOK);

  // cd_out = (h @ C) @ D
  lora_in_mfma<<<(TOK/16)*NPART/4, 256, 0, stream>>>(hbf, cpk, tpcd, TOK, INTER);
  lora_out<<<dim3(HID/1024, TOK/8), 256, 0, stream>>>(tpcd, Dmat, cd, HID, TOK);

  // out = h @ W_proj + b_proj
  gemm_bt<1><<<(TOK/256)*(HID/256), 512, 0, stream>>>(
      hbf, wpjt, bpj, nullptr, out, TOK, HID, INTER, HID/256);
}

// Round 11
// 1476.895 us; speedup vs baseline: 1.0663x; 1.0663x over previous
//
#include <hip/hip_runtime.h>
#include <math.h>

#define TOK   16384
#define HID   2048
#define INTER 8192
#define NPART 8

typedef __attribute__((ext_vector_type(8))) short short8;
typedef __attribute__((ext_vector_type(4))) float f32x4;

__device__ inline ushort f2bf(float f){
  union{float f; unsigned u;} v; v.f=f;
  unsigned r = v.u + 0x7FFFu + ((v.u>>16)&1u);
  return (ushort)(r>>16);
}

// ---------------- fp32 -> bf16 convert (row-major copy) ----------------
__global__ __launch_bounds__(256) void cvt_f32_bf16(const float* __restrict__ in,
                                                    ushort* __restrict__ out, int n4)
{
  int idx = blockIdx.x*blockDim.x + threadIdx.x;
  int stride = gridDim.x*blockDim.x;
  for (int i = idx; i < n4; i += stride) {
    float4 v = ((const float4*)in)[i];
    ushort4 o;
    o.x = f2bf(v.x); o.y = f2bf(v.y); o.z = f2bf(v.z); o.w = f2bf(v.w);
    ((ushort4*)out)[i] = o;
  }
}

// ---------------- transpose + convert: in[R][C] f32 -> out[C][R] bf16 ----------------
__global__ __launch_bounds__(256) void trans_cvt(const float* __restrict__ in,
                                                 ushort* __restrict__ out, int R, int C)
{
  __shared__ float t[32][33];
  int tx = threadIdx.x & 31, ty = threadIdx.x >> 5;
  int c0 = blockIdx.x*32, r0 = blockIdx.y*32;
  #pragma unroll
  for (int i = 0; i < 4; i++)
    t[ty + i*8][tx] = in[(size_t)(r0 + ty + i*8)*C + c0 + tx];
  __syncthreads();
  #pragma unroll
  for (int i = 0; i < 4; i++)
    out[(size_t)(c0 + ty + i*8)*R + r0 + tx] = f2bf(t[tx][ty + i*8]);
}

// ---------------- pack W[K][16] f32 -> B-fragment layout bf16 (LoRA) ----------------
__global__ __launch_bounds__(256) void pack_w(const float* __restrict__ W,
                                              ushort* __restrict__ out, int K)
{
  int tid = blockIdx.x*256 + threadIdx.x;
  int n = (K >> 5) * 64;
  if (tid >= n) return;
  int step = tid >> 6, l = tid & 63;
  int col = l & 15, kb = step*32 + ((l >> 4) << 3);
  ushort4 o0, o1;
  o0.x = f2bf(W[(size_t)(kb+0)*16 + col]);
  o0.y = f2bf(W[(size_t)(kb+1)*16 + col]);
  o0.z = f2bf(W[(size_t)(kb+2)*16 + col]);
  o0.w = f2bf(W[(size_t)(kb+3)*16 + col]);
  o1.x = f2bf(W[(size_t)(kb+4)*16 + col]);
  o1.y = f2bf(W[(size_t)(kb+5)*16 + col]);
  o1.z = f2bf(W[(size_t)(kb+6)*16 + col]);
  o1.w = f2bf(W[(size_t)(kb+7)*16 + col]);
  ((ushort4*)(out + (size_t)tid*8))[0] = o0;
  ((ushort4*)(out + (size_t)tid*8))[1] = o1;
}

// ---------------- rank-16 contract via MFMA, split-K partials ----------------
__global__ __launch_bounds__(256) void lora_in_mfma(const ushort* __restrict__ x,
                                                    const ushort* __restrict__ Wpk,
                                                    float* __restrict__ tpart,
                                                    int M, int K)
{
  const int l  = threadIdx.x & 63;
  const int wv = threadIdx.x >> 6;
  const int jid = blockIdx.x*4 + wv;
  const int nt = M >> 4;
  const int part = jid >> 10;
  const int tile = jid & (nt - 1);
  const int Kc = K / NPART;
  const int k0 = part * Kc;
  const int fr = l & 15, fq = l >> 4;

  const ushort* xp = x + (size_t)(tile*16 + fr)*K + k0 + fq*8;
  const ushort* wp = Wpk + (size_t)(k0 >> 5)*512 + l*8;

  f32x4 acc = (f32x4){0.f,0.f,0.f,0.f};
  const int ns = Kc >> 5;
  for (int s = 0; s < ns; ++s) {
    short8 av = *(const short8*)(xp + s*32);
    short8 bv = *(const short8*)(wp + s*512);
    acc = __builtin_amdgcn_mfma_f32_16x16x32_bf16(av, bv, acc, 0, 0, 0);
  }
  float* o = tpart + ((size_t)part*M + tile*16)*16;
  #pragma unroll
  for (int r = 0; r < 4; ++r) o[(fq*4 + r)*16 + fr] = acc[r];
}

// ---------------- rank-16 expand: out[N][W] = (sum_p tpart[p]) @ Bm[16][W] ----------------
__global__ __launch_bounds__(256) void lora_out(const float* __restrict__ tpart,
                                                const float* __restrict__ Bm,
                                                float* __restrict__ out, int W, int M)
{
  __shared__ float ts[8][16];
  int tid = threadIdx.x;
  int n0 = blockIdx.y*8, i0 = blockIdx.x*1024;
  if (tid < 128) {
    float s = 0.f;
    #pragma unroll
    for (int p = 0; p < NPART; ++p)
      s += tpart[((size_t)p*M + n0 + (tid>>4))*16 + (tid&15)];
    ts[tid>>4][tid&15] = s;
  }
  __syncthreads();
  const float4* B4 = (const float4*)Bm;
  float4 breg[16];
  #pragma unroll
  for (int r = 0; r < 16; r++) breg[r] = B4[(size_t)r*(W>>2) + (i0>>2) + tid];
  #pragma unroll
  for (int n = 0; n < 8; n++) {
    float4 o; o.x = o.y = o.z = o.w = 0.f;
    #pragma unroll
    for (int r = 0; r < 16; r++) {
      float s = ts[n][r];
      o.x += s*breg[r].x; o.y += s*breg[r].y; o.z += s*breg[r].z; o.w += s*breg[r].w;
    }
    ((float4*)(out + (size_t)(n0+n)*W + i0))[tid] = o;
  }
}

// =====================================================================
// m201-template 256x256 bf16 MFMA GEMM, BK=64, 8 waves (2Mx4N).
// 2-deep LDS double-buffer (128 KB), 4 phases/K-tile (16 MFMA each),
// 1 half-tile staged per phase, ONE counted vmcnt(4) per K-tile.
// FULL 3-bit XOR swizzle for 128B rows: chunk p = q ^ (row&7), applied
// on BOTH the ds_read side and the pre-swizzled global staging source.
// C = A[M][K] @ BT[N][K]^T + bias.  EPI=0: gelu->bf16; EPI=1: f32.
// =====================================================================
template<int EPI>
__global__ __launch_bounds__(512, 2)
void gemm_bt(const ushort* __restrict__ A,
             const ushort* __restrict__ BT,
             const float* __restrict__ bias,
             ushort* __restrict__ outb,
             float* __restrict__ outf,
             int M, int N, int K, int grid_n)
{
  // buffer: A[256][64] (32 KB) + B[256][64] (32 KB); x2 dbuf = 128 KB
  __shared__ __align__(16) ushort lds[2][32768];

  const int tid = threadIdx.x;
  const int l   = tid & 63;
  const int w   = tid >> 6;
  const int wr  = w >> 2;            // 0..1 (M half: 128 rows)
  const int wc  = w & 3;             // 0..3 (N quarter: 64 cols)

  const int nwg = gridDim.x;
  const int cpx = nwg >> 3;
  const int bid = blockIdx.x;
  const int wg  = (bid & 7) * cpx + (bid >> 3);
  const int bx  = wg % grid_n;
  const int by  = wg / grid_n;

  // staging: thread t writes physical chunk (t&7) of row (t>>3) per 64-row round;
  // global source carries inverse swizzle: logical chunk = (t&7) ^ ((t>>3)&7)
  const int srow8 = tid >> 3;                                // 0..63
  const int scol8 = (((tid & 7) ^ ((tid >> 3) & 7)) << 3);   // element offset
  const ushort* agp = A  + (size_t)(by*256 + srow8)*K + scol8;
  const ushort* bgp = BT + (size_t)(bx*256 + srow8)*K + scol8;

  // fragment read offsets: row r, k-step k, chunk q = fq + k*4,
  // physical chunk p = q ^ (r&7); r&7 == fr&7 for all m/n (offsets mult. of 8 rows)
  const int fr  = l & 15, fq = l >> 4;
  const int e7  = fr & 7;
  const int pk0 = (fq ^ e7) * 8;            // k=0 element offset within row
  const int pk1 = ((fq + 4) ^ e7) * 8;      // k=1
  const int arow = (wr*128 + fr) * 64;            // + m*1024
  const int brow = 16384 + (wc*64 + fr) * 64;     // + n*1024

  f32x4 acc[8][4];
  #pragma unroll
  for (int m = 0; m < 8; m++)
    #pragma unroll
    for (int n = 0; n < 4; n++) acc[m][n] = (f32x4){0.f,0.f,0.f,0.f};

  auto stA = [&](int u, int h) {     // A-half h (rows h*128..+127) of tile u
    ushort* d = &lds[u & 1][h*8192 + tid*8];
    const ushort* s = agp + (size_t)(h*128)*K + (size_t)u*64;
    __builtin_amdgcn_global_load_lds((const __attribute__((address_space(1))) void*)s,
                                     (__attribute__((address_space(3))) void*)d, 16, 0, 0);
    __builtin_amdgcn_global_load_lds((const __attribute__((address_space(1))) void*)(s + (size_t)64*K),
                                     (__attribute__((address_space(3))) void*)(d + 4096), 16, 0, 0);
  };
  auto stB = [&](int u, int h) {
    ushort* d = &lds[u & 1][16384 + h*8192 + tid*8];
    const ushort* s = bgp + (size_t)(h*128)*K + (size_t)u*64;
    __builtin_amdgcn_global_load_lds((const __attribute__((address_space(1))) void*)s,
                                     (__attribute__((address_space(3))) void*)d, 16, 0, 0);
    __builtin_amdgcn_global_load_lds((const __attribute__((address_space(1))) void*)(s + (size_t)64*K),
                                     (__attribute__((address_space(3))) void*)(d + 4096), 16, 0, 0);
  };

  const int nk = K >> 6;   // K-tiles of 64; >= 32 here

  // prologue: stage A(0), B(0), B(1); certify A(0)+B(0) (counted vmcnt)
  stA(0,0); stA(0,1); stB(0,0); stB(0,1); stB(1,0); stB(1,1);
  asm volatile("s_waitcnt vmcnt(4)" ::: "memory");
  __builtin_amdgcn_s_barrier();
  asm volatile("" ::: "memory");

  short8 a[8], b[8];

#define MFMA16(MBASE, NBASE) do {                                         \
    __builtin_amdgcn_s_setprio(1);                                        \
    _Pragma("unroll")                                                     \
    for (int m_ = 0; m_ < 4; ++m_)                                        \
      _Pragma("unroll")                                                   \
      for (int k_ = 0; k_ < 2; ++k_)                                      \
        _Pragma("unroll")                                                 \
        for (int n_ = 0; n_ < 2; ++n_)                                    \
          acc[MBASE + m_][NBASE + n_] = __builtin_amdgcn_mfma_f32_16x16x32_bf16( \
              b[(NBASE + n_)*2 + k_], a[m_*2 + k_], acc[MBASE + m_][NBASE + n_], 0,0,0); \
    __builtin_amdgcn_s_setprio(0);                                        \
  } while (0)

  for (int kt = 0; kt < nk; ++kt) {
    const ushort* Lb = &lds[kt & 1][0];

    // ---- phase 1: read A(m0-3) + B(n0-1); stage A(kt+1,h0); Q1 ----
    #pragma unroll
    for (int m = 0; m < 4; ++m) {
      a[m*2+0] = *(const short8*)(Lb + arow + m*1024 + pk0);
      a[m*2+1] = *(const short8*)(Lb + arow + m*1024 + pk1);
    }
    #pragma unroll
    for (int n = 0; n < 2; ++n) {
      b[n*2+0] = *(const short8*)(Lb + brow + n*1024 + pk0);
      b[n*2+1] = *(const short8*)(Lb + brow + n*1024 + pk1);
    }
    if (kt + 1 < nk) stA(kt+1, 0);
    __builtin_amdgcn_s_barrier();
    asm volatile("s_waitcnt lgkmcnt(0)" ::: "memory");
    __builtin_amdgcn_sched_barrier(0);
    MFMA16(0, 0);
    __builtin_amdgcn_s_barrier();
    asm volatile("" ::: "memory");

    // ---- phase 2: read B(n2-3); stage A(kt+1,h1); Q2 ----
    #pragma unroll
    for (int n = 2; n < 4; ++n) {
      b[n*2+0] = *(const short8*)(Lb + brow + n*1024 + pk0);
      b[n*2+1] = *(const short8*)(Lb + brow + n*1024 + pk1);
    }
    if (kt + 1 < nk) stA(kt+1, 1);
    __builtin_amdgcn_s_barrier();
    asm volatile("s_waitcnt lgkmcnt(0)" ::: "memory");
    __builtin_amdgcn_sched_barrier(0);
    MFMA16(0, 2);
    __builtin_amdgcn_s_barrier();
    asm volatile("" ::: "memory");

    // ---- phase 3: read A(m4-7); stage B(kt+2,h0); Q3 ----
    #pragma unroll
    for (int m = 0; m < 4; ++m) {
      a[m*2+0] = *(const short8*)(Lb + arow + (m+4)*1024 + pk0);
      a[m*2+1] = *(const short8*)(Lb + arow + (m+4)*1024 + pk1);
    }
    if (kt + 2 < nk) stB(kt+2, 0);
    __builtin_amdgcn_s_barrier();
    asm volatile("s_waitcnt lgkmcnt(0)" ::: "memory");
    __builtin_amdgcn_sched_barrier(0);
    MFMA16(4, 0);
    __builtin_amdgcn_s_barrier();
    asm volatile("" ::: "memory");

    // ---- phase 4: no reads; stage B(kt+2,h1); Q4; boundary ----
    if (kt + 2 < nk) stB(kt+2, 1);
    __builtin_amdgcn_s_barrier();
    asm volatile("" ::: "memory");
    MFMA16(4, 2);
    if (kt + 1 < nk) {
      if (kt + 2 < nk) asm volatile("s_waitcnt vmcnt(4)" ::: "memory");
      else             asm volatile("s_waitcnt vmcnt(0)" ::: "memory");
      __builtin_amdgcn_s_barrier();
      asm volatile("" ::: "memory");
    }
  }

#undef MFMA16

  // ---- epilogue: lane&15 = M-row, (lane>>4)*4+r = N-col -> vector stores ----
  #pragma unroll
  for (int m = 0; m < 8; ++m) {
    const int rowg = by*256 + wr*128 + m*16 + fr;
    #pragma unroll
    for (int n = 0; n < 4; ++n) {
      const int colg = bx*256 + wc*64 + n*16 + fq*4;
      const float4 bv = *(const float4*)&bias[colg];
      float v0 = acc[m][n][0] + bv.x;
      float v1 = acc[m][n][1] + bv.y;
      float v2 = acc[m][n][2] + bv.z;
      float v3 = acc[m][n][3] + bv.w;
      if (EPI == 0) {
        #define GELU(v) do { \
          float u_ = 0.7978845608028654f*((v) + 0.044715f*(v)*(v)*(v)); \
          float e_ = __builtin_amdgcn_exp2f(-2.8853900817779268f*u_);   \
          (v) = (v) * __builtin_amdgcn_rcpf(1.0f + e_); } while(0)
        GELU(v0); GELU(v1); GELU(v2); GELU(v3);
        #undef GELU
        ushort4 o; o.x = f2bf(v0); o.y = f2bf(v1); o.z = f2bf(v2); o.w = f2bf(v3);
        *(ushort4*)&outb[(size_t)rowg*N + colg] = o;
      } else {
        float4 o; o.x = v0; o.y = v1; o.z = v2; o.w = v3;
        *(float4*)&outf[(size_t)rowg*N + colg] = o;
      }
    }
  }
}

extern "C" void kernel_launch(void* const* d_in, const int* in_sizes, int n_in,
                              void* d_out, int out_size, void* d_ws, size_t ws_size,
                              hipStream_t stream)
{
  const float* hid  = (const float*)d_in[0];
  const float* Wfc  = (const float*)d_in[1];
  const float* bfc  = (const float*)d_in[2];
  const float* Wpj  = (const float*)d_in[3];
  const float* bpj  = (const float*)d_in[4];
  const float* Amat = (const float*)d_in[5];
  const float* Bmat = (const float*)d_in[6];
  const float* Cmat = (const float*)d_in[7];
  const float* Dmat = (const float*)d_in[8];

  float* out = (float*)d_out;                  // [TOK][HID]
  float* ab  = out + (size_t)TOK*HID;          // [TOK][INTER]
  float* cd  = ab  + (size_t)TOK*INTER;        // [TOK][HID]

  char* ws = (char*)d_ws;
  ushort* hidb = (ushort*)ws;  ws += (size_t)TOK*HID*2;
  ushort* wfct = (ushort*)ws;  ws += (size_t)INTER*HID*2;
  ushort* wpjt = (ushort*)ws;  ws += (size_t)HID*INTER*2;
  ushort* hbf  = (ushort*)ws;  ws += (size_t)TOK*INTER*2;
  ushort* apk  = (ushort*)ws;  ws += (size_t)HID*16*2;
  ushort* cpk  = (ushort*)ws;  ws += (size_t)INTER*16*2;
  float*  tpab = (float*)ws;   ws += (size_t)NPART*TOK*16*4;
  float*  tpcd = (float*)ws;   ws += (size_t)NPART*TOK*16*4;

  // independent pre-passes
  cvt_f32_bf16<<<4096, 256, 0, stream>>>(hid, hidb, TOK*HID/4);
  trans_cvt<<<dim3(INTER/32, HID/32), 256, 0, stream>>>(Wfc, wfct, HID, INTER);
  trans_cvt<<<dim3(HID/32, INTER/32), 256, 0, stream>>>(Wpj, wpjt, INTER, HID);
  pack_w<<<((HID/32)*64 + 255)/256, 256, 0, stream>>>(Amat, apk, HID);
  pack_w<<<((INTER/32)*64 + 255)/256, 256, 0, stream>>>(Cmat, cpk, INTER);

  // t_ab partials = hidden @ A
  lora_in_mfma<<<(TOK/16)*NPART/4, 256, 0, stream>>>(hidb, apk, tpab, TOK, HID);

  // h = gelu(hidden @ W_fc + b_fc), stored bf16
  gemm_bt<0><<<(TOK/256)*(INTER/256), 512, 0, stream>>>(
      hidb, wfct, bfc, hbf, nullptr, TOK, INTER, HID, INTER/256);

  // ab_out = (hidden @ A) @ B
  lora_out<<<dim3(INTER/1024, TOK/8), 256, 0, stream>>>(tpab, Bmat, ab, INTER, TOK);

  // cd_out = (h @ C) @ D
  lora_in_mfma<<<(TOK/16)*NPART/4, 256, 0, stream>>>(hbf, cpk, tpcd, TOK, INTER);
  lora_out<<<dim3(HID/1024, TOK/8), 256, 0, stream>>>(tpcd, Dmat, cd, HID, TOK);

  // out = h @ W_proj + b_proj
  gemm_bt<1><<<(TOK/256)*(HID/256), 512, 0, stream>>>(
      hbf, wpjt, bpj, nullptr, out, TOK, HID, INTER, HID/256);
}